// Round 2
// baseline (421.760 us; speedup 1.0000x reference)
//
#include <hip/hip_runtime.h>
#include <hip/hip_bf16.h>

#define B_TOT 32768
#define W 5
#define L 20
#define CE 32
#define OC 30
#define KW 3
#define WE 50
#define HID 100
#define TAGS 36
#define CV 100
#define FEAT 400          // (WE+OC)*W

#define NI 8              // items per block
#define SF 404            // feats LDS stride (floats): rows 16B-aligned, distinct bank phase per item
#define SH 101            // h LDS stride

// T[k][c][oc] = sum_ce conv_w[oc][ce][k] * char_emb[c][ce]
__global__ void precompute_T(const float* __restrict__ conv_w,
                             const float* __restrict__ char_emb,
                             float* __restrict__ T) {
    int idx = blockIdx.x * blockDim.x + threadIdx.x;
    if (idx >= 3 * CV * OC) return;
    int oc = idx % OC;
    int c  = (idx / OC) % CV;
    int k  = idx / (OC * CV);
    float s = 0.f;
    #pragma unroll
    for (int ce = 0; ce < CE; ++ce) {
        s += char_emb[c * CE + ce] * conv_w[(oc * CE + ce) * KW + k];
    }
    T[idx] = s;
}

__global__ __launch_bounds__(256)
void pos_main(const int*   __restrict__ input,   // (B, W, 21) int32
              const float* __restrict__ emb,     // (WV, WE)
              const float* __restrict__ conv_b,  // (OC)
              const float* __restrict__ fc1_w,   // (HID, 400)
              const float* __restrict__ fc1_b,   // (HID)
              const float* __restrict__ out_w,   // (TAGS, HID)
              const float* __restrict__ out_b,   // (TAGS)
              const float* __restrict__ T,       // (3, CV, OC) fp32 (in ws)
              float*       __restrict__ out)     // (B, TAGS)
{
    __shared__ float Ts[3 * CV * OC];             // 36000 B
    __shared__ int   ids[NI][W * (1 + L)];        // 3360 B
    __shared__ float feats[NI][SF];               // 12928 B
    __shared__ float hbuf[NI][SH];                // 3232 B

    const int tid   = threadIdx.x;
    const int item0 = blockIdx.x * NI;

    // ---- stage T table + input ids ----
    for (int i = tid; i < 3 * CV * OC; i += 256) Ts[i] = T[i];
    const int* inp = input + (long long)item0 * (W * (1 + L));
    for (int i = tid; i < NI * W * (1 + L); i += 256) (&ids[0][0])[i] = inp[i];
    __syncthreads();

    // ---- word-embedding part of feats: NI*W*WE = 2000 tasks ----
    for (int idx = tid; idx < NI * W * WE; idx += 256) {
        int j = idx % WE;
        int w = (idx / WE) % W;
        int i = idx / (WE * W);
        int wid = ids[i][w * (1 + L)];
        feats[i][w * 80 + j] = emb[wid * WE + j];
    }
    // ---- conv + maxpool part: NI*W*OC = 1200 tasks ----
    for (int idx = tid; idx < NI * W * OC; idx += 256) {
        int oc = idx % OC;
        int w  = (idx / OC) % W;
        int i  = idx / (OC * W);
        const int* cp = &ids[i][w * (1 + L) + 1];
        int c[L];
        #pragma unroll
        for (int p = 0; p < L; ++p) c[p] = cp[p];
        float m = -1e30f;
        #pragma unroll
        for (int p = 0; p < L - KW + 1; ++p) {
            float s = Ts[(0 * CV + c[p    ]) * OC + oc]
                    + Ts[(1 * CV + c[p + 1]) * OC + oc]
                    + Ts[(2 * CV + c[p + 2]) * OC + oc];
            m = fmaxf(m, s);
        }
        feats[i][w * 80 + WE + oc] = m + conv_b[oc];
    }
    __syncthreads();

    // ---- fc1: each thread = 1 item x 4 hidden (j = jb + 32r) ----
    {
        const int i  = tid & 7;
        const int jb = tid >> 3;            // 0..31
        float acc[4] = {0.f, 0.f, 0.f, 0.f};
        const float* fr = feats[i];
        for (int k = 0; k < FEAT; k += 8) {
            float4 f0 = *(const float4*)&fr[k];
            float4 f1 = *(const float4*)&fr[k + 4];
            #pragma unroll
            for (int r = 0; r < 4; ++r) {
                int j = jb + 32 * r;
                if (j < HID) {
                    float4 w0 = *(const float4*)&fc1_w[j * FEAT + k];
                    float4 w1 = *(const float4*)&fc1_w[j * FEAT + k + 4];
                    float a = acc[r];
                    a = fmaf(w0.x, f0.x, a);
                    a = fmaf(w0.y, f0.y, a);
                    a = fmaf(w0.z, f0.z, a);
                    a = fmaf(w0.w, f0.w, a);
                    a = fmaf(w1.x, f1.x, a);
                    a = fmaf(w1.y, f1.y, a);
                    a = fmaf(w1.z, f1.z, a);
                    a = fmaf(w1.w, f1.w, a);
                    acc[r] = a;
                }
            }
        }
        #pragma unroll
        for (int r = 0; r < 4; ++r) {
            int j = jb + 32 * r;
            if (j < HID) hbuf[i][j] = tanhf(acc[r] + fc1_b[j]);
        }
    }
    __syncthreads();

    // ---- output layer: NI*TAGS = 288 tasks ----
    for (int idx = tid; idx < NI * TAGS; idx += 256) {
        int i = idx & 7;
        int o = idx >> 3;
        float acc = out_b[o];
        const float* hr = hbuf[i];
        #pragma unroll 4
        for (int k = 0; k < HID; ++k)
            acc = fmaf(hr[k], out_w[o * HID + k], acc);
        out[(item0 + i) * TAGS + o] = acc;
    }
}

extern "C" void kernel_launch(void* const* d_in, const int* in_sizes, int n_in,
                              void* d_out, int out_size, void* d_ws, size_t ws_size,
                              hipStream_t stream) {
    const int*   input  = (const int*)  d_in[0];
    const float* emb    = (const float*)d_in[1];
    const float* char_e = (const float*)d_in[2];
    const float* conv_w = (const float*)d_in[3];
    const float* conv_b = (const float*)d_in[4];
    const float* fc1_w  = (const float*)d_in[5];
    const float* fc1_b  = (const float*)d_in[6];
    const float* out_w  = (const float*)d_in[7];
    const float* out_b  = (const float*)d_in[8];
    float* T = (float*)d_ws;   // 9000 floats = 36 KB scratch

    precompute_T<<<(3 * CV * OC + 255) / 256, 256, 0, stream>>>(conv_w, char_e, T);
    pos_main<<<B_TOT / NI, 256, 0, stream>>>(input, emb, conv_b, fc1_w, fc1_b,
                                             out_w, out_b, T, (float*)d_out);
}

// Round 3
// 140.615 us; speedup vs baseline: 2.9994x; 2.9994x over previous
//
#include <hip/hip_runtime.h>
#include <hip/hip_bf16.h>

#define B_TOT 32768
#define W 5
#define OC 30
#define WE 50
#define HID 100
#define TAGS 36
#define CV 100

#define NI 32             // items per block
#define FS 212            // feats LDS stride in dwords (424 bf16: 416 K-pad + 8 bank-pad)
#define HS 68             // h LDS stride in dwords (136 bf16: 128 K-pad + 8 bank-pad)

// ws layout (bytes): Ts2 u32[4800] @0 ; fc1wp uint4 @19456 (93184 B); outwp uint4 @112640 (12288 B)
#define WS_FC1 19456
#define WS_OUT 112640

typedef __attribute__((ext_vector_type(8))) short short8;
typedef __attribute__((ext_vector_type(4))) float f32x4;

__device__ inline float bflo(unsigned int u) {
    union { unsigned int i; float f; } v; v.i = u << 16; return v.f;
}
__device__ inline float bfhi(unsigned int u) {
    union { unsigned int i; float f; } v; v.i = u & 0xFFFF0000u; return v.f;
}
__device__ inline unsigned short f2bf(float f) {
    __hip_bfloat16 h = __float2bfloat16(f);
    return *reinterpret_cast<unsigned short*>(&h);
}
__device__ inline unsigned int pk_bf16(float a, float b) {
    return (unsigned int)f2bf(a) | ((unsigned int)f2bf(b) << 16);
}
__device__ inline short8 as8(uint4 u) {
    union { uint4 a; short8 b; } v; v.a = u; return v.b;
}

// ---------------- prep: pack T table + fc1_w + out_w into MFMA-friendly bf16 ----------------
__global__ void prep(const float* __restrict__ conv_w,   // (30,32,3)
                     const float* __restrict__ char_emb, // (100,32)
                     const float* __restrict__ fc1_w,    // (100,400)
                     const float* __restrict__ out_w,    // (36,100)
                     unsigned int* __restrict__ ws) {
    int idx = blockIdx.x * 256 + threadIdx.x;
    if (idx < 4800) {
        // Ts2[k][c][q] = pack(T(k,c,2q), T(k,c,2q+1)), T = sum_ce char_emb[c][ce]*conv_w[oc][ce][k]
        int q = idx % 16, c = (idx / 16) % 100, k = idx / 1600;
        float v[2];
        #pragma unroll
        for (int e = 0; e < 2; ++e) {
            int oc = 2 * q + e;
            float s = 0.f;
            if (oc < OC) {
                for (int ce = 0; ce < 32; ++ce)
                    s += char_emb[c * 32 + ce] * conv_w[(oc * 32 + ce) * 3 + k];
            }
            v[e] = s;
        }
        ws[idx] = pk_bf16(v[0], v[1]);
    } else if (idx < 4800 + 23296) {
        // fc1 B-frag chunks: [(nt*13+ks)][lane][dw] ; n=lane&15, k=ks*32+(lane>>4)*8+dw*2
        int t = idx - 4800;
        int dw = t & 3, lane = (t >> 2) & 63, chunk = t >> 8;
        int ks = chunk % 13, nt = chunk / 13;
        int j = nt * 16 + (lane & 15);
        int k = ks * 32 + (lane >> 4) * 8 + dw * 2;
        float a = (j < HID && k     < 400) ? fc1_w[j * 400 + k]     : 0.f;
        float b = (j < HID && k + 1 < 400) ? fc1_w[j * 400 + k + 1] : 0.f;
        ((unsigned int*)((char*)ws + WS_FC1))[t] = pk_bf16(a, b);
    } else if (idx < 4800 + 23296 + 3072) {
        int t = idx - 28096;
        int dw = t & 3, lane = (t >> 2) & 63, chunk = t >> 8;
        int ks = chunk % 4, nt = chunk / 4;
        int j = nt * 16 + (lane & 15);
        int k = ks * 32 + (lane >> 4) * 8 + dw * 2;
        float a = (j < TAGS && k     < HID) ? out_w[j * 100 + k]     : 0.f;
        float b = (j < TAGS && k + 1 < HID) ? out_w[j * 100 + k + 1] : 0.f;
        ((unsigned int*)((char*)ws + WS_OUT))[t] = pk_bf16(a, b);
    }
}

// ---------------- fused main ----------------
__global__ __launch_bounds__(256)
void pos_fused(const int*   __restrict__ input,   // (B, 105)
               const float* __restrict__ emb,     // (WV, 50)
               const float* __restrict__ conv_b,  // (30)
               const float* __restrict__ fc1_b,   // (100)
               const float* __restrict__ out_b,   // (36)
               const unsigned int* __restrict__ ws,
               float*       __restrict__ out)     // (B, 36)
{
    __shared__ unsigned int F[NI * FS];   // feats bf16x2, A-layout, 27136 B
    __shared__ unsigned int Ts2[4800];    // packed T table, 19200 B
    __shared__ int          ids[NI * 105];// 13440 B
    __shared__ unsigned int Hh[NI * HS];  // h bf16x2, 8704 B

    const int tid   = threadIdx.x;
    const int item0 = blockIdx.x * NI;

    // ---- stage table + ids, zero K-pads ----
    for (int idx = tid; idx < 4800; idx += 256) Ts2[idx] = ws[idx];
    const int* inp = input + item0 * 105;
    for (int idx = tid; idx < NI * 105; idx += 256) ids[idx] = inp[idx];
    for (int idx = tid; idx < NI * 12; idx += 256) F[(idx / 12) * FS + 200 + idx % 12] = 0;
    for (int idx = tid; idx < NI * 18; idx += 256) Hh[(idx / 18) * HS + 50 + idx % 18] = 0;
    __syncthreads();

    // ---- word embeddings -> F (bf16 pairs) ----
    for (int idx = tid; idx < NI * 5 * 25; idx += 256) {
        int ph = idx % 25;
        int w  = (idx / 25) % 5;
        int i  = idx / 125;
        int wid = ids[i * 105 + w * 21];
        float2 e = *(const float2*)&emb[wid * 50 + ph * 2];
        F[i * FS + w * 40 + ph] = pk_bf16(e.x, e.y);
    }

    // ---- conv + maxpool: 8 lanes per (i,w) task, lane covers 4 oc via b64 ----
    {
        const int q8  = tid & 7;
        const int grp = tid >> 3;                 // 0..31
        for (int round = 0; round < 5; ++round) {
            int task = round * 32 + grp;          // 0..159
            int i = task / 5, w = task % 5;
            const int* cp = &ids[i * 105 + w * 21 + 1];
            int c[20];
            #pragma unroll
            for (int p = 0; p < 20; ++p) c[p] = cp[p];
            float m0 = -1e30f, m1 = -1e30f, m2 = -1e30f, m3 = -1e30f;
            #pragma unroll
            for (int p = 0; p < 18; ++p) {
                uint2 t0 = *(const uint2*)&Ts2[(      c[p    ]) * 16 + q8 * 2];
                uint2 t1 = *(const uint2*)&Ts2[(100 + c[p + 1]) * 16 + q8 * 2];
                uint2 t2 = *(const uint2*)&Ts2[(200 + c[p + 2]) * 16 + q8 * 2];
                float s0 = bflo(t0.x) + bflo(t1.x) + bflo(t2.x);
                float s1 = bfhi(t0.x) + bfhi(t1.x) + bfhi(t2.x);
                float s2 = bflo(t0.y) + bflo(t1.y) + bflo(t2.y);
                float s3 = bfhi(t0.y) + bfhi(t1.y) + bfhi(t2.y);
                m0 = fmaxf(m0, s0); m1 = fmaxf(m1, s1);
                m2 = fmaxf(m2, s2); m3 = fmaxf(m3, s3);
            }
            int oc0 = q8 * 4;
            float b0 = conv_b[oc0], b1 = conv_b[oc0 + 1];
            F[i * FS + w * 40 + 25 + q8 * 2] = pk_bf16(m0 + b0, m1 + b1);
            if (oc0 + 2 < OC) {
                float b2 = conv_b[oc0 + 2], b3 = conv_b[oc0 + 3];
                F[i * FS + w * 40 + 25 + q8 * 2 + 1] = pk_bf16(m2 + b2, m3 + b3);
            }
        }
    }
    __syncthreads();

    // ---- fc1: MFMA 16x16x32 bf16. wave -> (msub, n-half) ----
    const int wv   = tid >> 6;
    const int lane = tid & 63;
    const int ln15 = lane & 15;
    const int quad = lane >> 4;
    {
        const int msub = wv & 1;
        const int nh   = wv >> 1;
        const int nt0  = nh * 4;
        const int NT   = nh ? 3 : 4;               // n-tiles 0..3 / 4..6 (N=112)
        const int m0   = msub * 16;
        f32x4 acc[4] = {f32x4{0,0,0,0}, f32x4{0,0,0,0}, f32x4{0,0,0,0}, f32x4{0,0,0,0}};
        const uint4* wp = (const uint4*)((const char*)ws + WS_FC1);
        const int aoff = (m0 + ln15) * FS + quad * 4;
        for (int ks = 0; ks < 13; ++ks) {
            short8 a = as8(*(const uint4*)&F[aoff + ks * 16]);
            #pragma unroll
            for (int t = 0; t < 4; ++t) {
                if (t < NT) {
                    uint4 bv = wp[((nt0 + t) * 13 + ks) * 64 + lane];
                    acc[t] = __builtin_amdgcn_mfma_f32_16x16x32_bf16(a, as8(bv), acc[t], 0, 0, 0);
                }
            }
        }
        #pragma unroll
        for (int t = 0; t < 4; ++t) {
            if (t < NT) {
                int j = (nt0 + t) * 16 + ln15;     // C col = lane&15
                if (j < HID) {
                    float bj = fc1_b[j];
                    #pragma unroll
                    for (int r = 0; r < 4; ++r) {
                        int it = m0 + quad * 4 + r; // C row = quad*4+reg
                        float hv = tanhf(acc[t][r] + bj);
                        ((unsigned short*)Hh)[it * (HS * 2) + j] = f2bf(hv);
                    }
                }
            }
        }
    }
    __syncthreads();

    // ---- out layer: MFMA, N=48 (3 tiles), K=128 (4 steps) ----
    {
        const int msub = wv & 1;
        const int nh   = wv >> 1;
        const int nt0  = nh * 2;
        const int NT   = nh ? 1 : 2;               // n-tiles 0,1 / 2
        const int m0   = msub * 16;
        f32x4 acc[2] = {f32x4{0,0,0,0}, f32x4{0,0,0,0}};
        const uint4* wp = (const uint4*)((const char*)ws + WS_OUT);
        const int aoff = (m0 + ln15) * HS + quad * 4;
        #pragma unroll
        for (int ks = 0; ks < 4; ++ks) {
            short8 a = as8(*(const uint4*)&Hh[aoff + ks * 16]);
            #pragma unroll
            for (int t = 0; t < 2; ++t) {
                if (t < NT) {
                    uint4 bv = wp[((nt0 + t) * 4 + ks) * 64 + lane];
                    acc[t] = __builtin_amdgcn_mfma_f32_16x16x32_bf16(a, as8(bv), acc[t], 0, 0, 0);
                }
            }
        }
        #pragma unroll
        for (int t = 0; t < 2; ++t) {
            if (t < NT) {
                int o = (nt0 + t) * 16 + ln15;
                if (o < TAGS) {
                    float bo = out_b[o];
                    #pragma unroll
                    for (int r = 0; r < 4; ++r) {
                        int it = item0 + m0 + quad * 4 + r;
                        out[it * TAGS + o] = acc[t][r] + bo;
                    }
                }
            }
        }
    }
}

extern "C" void kernel_launch(void* const* d_in, const int* in_sizes, int n_in,
                              void* d_out, int out_size, void* d_ws, size_t ws_size,
                              hipStream_t stream) {
    const int*   input  = (const int*)  d_in[0];
    const float* emb    = (const float*)d_in[1];
    const float* char_e = (const float*)d_in[2];
    const float* conv_w = (const float*)d_in[3];
    const float* conv_b = (const float*)d_in[4];
    const float* fc1_w  = (const float*)d_in[5];
    const float* fc1_b  = (const float*)d_in[6];
    const float* out_w  = (const float*)d_in[7];
    const float* out_b  = (const float*)d_in[8];
    unsigned int* ws = (unsigned int*)d_ws;

    prep<<<122, 256, 0, stream>>>(conv_w, char_e, fc1_w, out_w, ws);
    pos_fused<<<B_TOT / NI, 256, 0, stream>>>(input, emb, conv_b, fc1_b, out_b,
                                              ws, (float*)d_out);
}

// Round 4
// 133.692 us; speedup vs baseline: 3.1547x; 1.0518x over previous
//
#include <hip/hip_runtime.h>
#include <hip/hip_bf16.h>

#define B_TOT 32768
#define W 5
#define OC 30
#define WE 50
#define HID 100
#define TAGS 36

#define NI 32             // items per block
#define FS 212            // feats LDS stride in dwords (424 bf16: 416 K-pad + pad; %4==0, %32==20)
#define HS 68             // h LDS stride in dwords (136 bf16: 128 K-pad + pad)

// ws layout (dwords): Tsf f32[9600] @0 ; fc1 pack u32[23296] @9600 ; out pack u32[3072] @32896
#define WS_FC1_DW 9600
#define WS_OUT_DW 32896

typedef __attribute__((ext_vector_type(8))) short short8;
typedef __attribute__((ext_vector_type(4))) float f32x4;

__device__ inline unsigned short f2bf(float f) {
    __hip_bfloat16 h = __float2bfloat16(f);
    return *reinterpret_cast<unsigned short*>(&h);
}
__device__ inline unsigned int pk_bf16(float a, float b) {
    return (unsigned int)f2bf(a) | ((unsigned int)f2bf(b) << 16);
}
__device__ inline short8 as8(uint4 u) {
    union { uint4 a; short8 b; } v; v.a = u; return v.b;
}

// ---------------- prep: fp32 T table + bf16 MFMA B-fragment packs ----------------
__global__ void prep(const float* __restrict__ conv_w,   // (30,32,3)
                     const float* __restrict__ char_emb, // (100,32)
                     const float* __restrict__ fc1_w,    // (100,400)
                     const float* __restrict__ out_w,    // (36,100)
                     unsigned int* __restrict__ ws) {
    int idx = blockIdx.x * 256 + threadIdx.x;
    if (idx < 9600) {
        // Tsf[k][c][oc32]: fp32, oc padded to 32 (zeros) -> conflict-free float4 reads
        int oc = idx & 31, c = (idx >> 5) % 100, k = idx / 3200;
        float s = 0.f;
        if (oc < OC) {
            for (int ce = 0; ce < 32; ++ce)
                s += char_emb[c * 32 + ce] * conv_w[(oc * 32 + ce) * 3 + k];
        }
        ((float*)ws)[idx] = s;
    } else if (idx < 9600 + 23296) {
        // fc1 B-frag chunks: [(nt*13+ks)][lane][dw] ; n=lane&15, k=ks*32+(lane>>4)*8+dw*2
        int t = idx - 9600;
        int dw = t & 3, lane = (t >> 2) & 63, chunk = t >> 8;
        int ks = chunk % 13, nt = chunk / 13;
        int j = nt * 16 + (lane & 15);
        int k = ks * 32 + (lane >> 4) * 8 + dw * 2;
        float a = (j < HID && k     < 400) ? fc1_w[j * 400 + k]     : 0.f;
        float b = (j < HID && k + 1 < 400) ? fc1_w[j * 400 + k + 1] : 0.f;
        ws[WS_FC1_DW + t] = pk_bf16(a, b);
    } else if (idx < 9600 + 23296 + 3072) {
        int t = idx - (9600 + 23296);
        int dw = t & 3, lane = (t >> 2) & 63, chunk = t >> 8;
        int ks = chunk % 4, nt = chunk / 4;
        int j = nt * 16 + (lane & 15);
        int k = ks * 32 + (lane >> 4) * 8 + dw * 2;
        float a = (j < TAGS && k     < HID) ? out_w[j * 100 + k]     : 0.f;
        float b = (j < TAGS && k + 1 < HID) ? out_w[j * 100 + k + 1] : 0.f;
        ws[WS_OUT_DW + t] = pk_bf16(a, b);
    }
}

// ---------------- fused main ----------------
__global__ __launch_bounds__(256)
void pos_fused(const int*   __restrict__ input,   // (B, 105)
               const float* __restrict__ emb,     // (WV, 50)
               const float* __restrict__ conv_b,  // (30)
               const float* __restrict__ fc1_b,   // (100)
               const float* __restrict__ out_b,   // (36)
               const unsigned int* __restrict__ ws,
               float*       __restrict__ out)     // (B, 36)
{
    __shared__ unsigned int F[NI * FS];   // feats bf16x2, A-layout, 27136 B
    __shared__ float        Tsf[9600];    // fp32 T table [k][c][32], 38400 B
    __shared__ unsigned int Hh[NI * HS];  // h bf16x2, 8704 B

    const int tid   = threadIdx.x;
    const int item0 = blockIdx.x * NI;

    // ---- stage fp32 T table; zero K-pads ----
    for (int idx = tid; idx < 9600; idx += 256) Tsf[idx] = ((const float*)ws)[idx];
    for (int idx = tid; idx < NI * 12; idx += 256) F[(idx / 12) * FS + 200 + idx % 12] = 0;
    for (int idx = tid; idx < NI * 18; idx += 256) Hh[(idx / 18) * HS + 50 + idx % 18] = 0;

    // ---- word embeddings -> F (bf16 pairs); ids straight from global (L1) ----
    for (int idx = tid; idx < NI * 5 * 25; idx += 256) {
        int ph = idx % 25;
        int w  = (idx / 25) % 5;
        int i  = idx / 125;
        int wid = input[(item0 + i) * 105 + w * 21];
        float2 e = *(const float2*)&emb[wid * 50 + ph * 2];
        F[i * FS + w * 40 + ph] = pk_bf16(e.x, e.y);
    }
    __syncthreads();   // Tsf ready

    // ---- conv + maxpool: 8 lanes per (i,w) task, lane = 4 oc via fp32 float4 ----
    {
        const int q8  = tid & 7;
        const int grp = tid >> 3;                 // 0..31
        const int oc0 = q8 * 4;
        for (int round = 0; round < 5; ++round) {
            int task = round * 32 + grp;          // 0..159
            int i = task / 5, w = task % 5;
            const int* cp = &input[(item0 + i) * 105 + w * 21 + 1];
            int c[20];
            #pragma unroll
            for (int p = 0; p < 20; ++p) c[p] = cp[p];
            float m0 = -1e30f, m1 = -1e30f, m2 = -1e30f, m3 = -1e30f;
            #pragma unroll
            for (int p = 0; p < 18; ++p) {
                float4 t0 = *(const float4*)&Tsf[(       c[p    ]) * 32 + oc0];
                float4 t1 = *(const float4*)&Tsf[(3200 + c[p + 1] * 32) + oc0];
                float4 t2 = *(const float4*)&Tsf[(6400 + c[p + 2] * 32) + oc0];
                float s0 = t0.x + t1.x + t2.x;
                float s1 = t0.y + t1.y + t2.y;
                float s2 = t0.z + t1.z + t2.z;
                float s3 = t0.w + t1.w + t2.w;
                m0 = fmaxf(m0, s0); m1 = fmaxf(m1, s1);
                m2 = fmaxf(m2, s2); m3 = fmaxf(m3, s3);
            }
            float b0 = conv_b[oc0], b1 = conv_b[oc0 + 1];
            F[i * FS + w * 40 + 25 + q8 * 2] = pk_bf16(m0 + b0, m1 + b1);
            if (oc0 + 2 < OC) {
                float b2 = conv_b[oc0 + 2], b3 = conv_b[oc0 + 3];
                F[i * FS + w * 40 + 25 + q8 * 2 + 1] = pk_bf16(m2 + b2, m3 + b3);
            }
        }
    }
    __syncthreads();   // F ready

    // ---- fc1: MFMA 16x16x32 bf16. wave -> (msub, n-half) ----
    const int wv   = tid >> 6;
    const int lane = tid & 63;
    const int ln15 = lane & 15;
    const int quad = lane >> 4;
    {
        const int msub = wv & 1;
        const int nh   = wv >> 1;
        const int nt0  = nh * 4;
        const int NT   = nh ? 3 : 4;               // n-tiles 0..3 / 4..6 (N=112)
        const int m0   = msub * 16;
        f32x4 acc[4] = {f32x4{0,0,0,0}, f32x4{0,0,0,0}, f32x4{0,0,0,0}, f32x4{0,0,0,0}};
        const uint4* wp = (const uint4*)(ws + WS_FC1_DW);
        const int aoff = (m0 + ln15) * FS + quad * 4;
        for (int ks = 0; ks < 13; ++ks) {
            short8 a = as8(*(const uint4*)&F[aoff + ks * 16]);
            #pragma unroll
            for (int t = 0; t < 4; ++t) {
                if (t < NT) {
                    uint4 bv = wp[((nt0 + t) * 13 + ks) * 64 + lane];
                    acc[t] = __builtin_amdgcn_mfma_f32_16x16x32_bf16(a, as8(bv), acc[t], 0, 0, 0);
                }
            }
        }
        #pragma unroll
        for (int t = 0; t < 4; ++t) {
            if (t < NT) {
                int j = (nt0 + t) * 16 + ln15;     // C col = lane&15
                if (j < HID) {
                    float bj = fc1_b[j];
                    #pragma unroll
                    for (int r = 0; r < 4; ++r) {
                        int it = m0 + quad * 4 + r; // C row = quad*4+reg
                        float hv = tanhf(acc[t][r] + bj);
                        ((unsigned short*)Hh)[it * (HS * 2) + j] = f2bf(hv);
                    }
                }
            }
        }
    }
    __syncthreads();   // Hh ready

    // ---- out layer: MFMA, N=48 (3 tiles), K=128 (4 steps) ----
    {
        const int msub = wv & 1;
        const int nh   = wv >> 1;
        const int nt0  = nh * 2;
        const int NT   = nh ? 1 : 2;               // n-tiles 0,1 / 2
        const int m0   = msub * 16;
        f32x4 acc[2] = {f32x4{0,0,0,0}, f32x4{0,0,0,0}};
        const uint4* wp = (const uint4*)(ws + WS_OUT_DW);
        const int aoff = (m0 + ln15) * HS + quad * 4;
        #pragma unroll
        for (int ks = 0; ks < 4; ++ks) {
            short8 a = as8(*(const uint4*)&Hh[aoff + ks * 16]);
            #pragma unroll
            for (int t = 0; t < 2; ++t) {
                if (t < NT) {
                    uint4 bv = wp[((nt0 + t) * 4 + ks) * 64 + lane];
                    acc[t] = __builtin_amdgcn_mfma_f32_16x16x32_bf16(a, as8(bv), acc[t], 0, 0, 0);
                }
            }
        }
        #pragma unroll
        for (int t = 0; t < 2; ++t) {
            if (t < NT) {
                int o = (nt0 + t) * 16 + ln15;
                if (o < TAGS) {
                    float bo = out_b[o];
                    #pragma unroll
                    for (int r = 0; r < 4; ++r) {
                        int it = item0 + m0 + quad * 4 + r;
                        out[it * TAGS + o] = acc[t][r] + bo;
                    }
                }
            }
        }
    }
}

extern "C" void kernel_launch(void* const* d_in, const int* in_sizes, int n_in,
                              void* d_out, int out_size, void* d_ws, size_t ws_size,
                              hipStream_t stream) {
    const int*   input  = (const int*)  d_in[0];
    const float* emb    = (const float*)d_in[1];
    const float* char_e = (const float*)d_in[2];
    const float* conv_w = (const float*)d_in[3];
    const float* conv_b = (const float*)d_in[4];
    const float* fc1_w  = (const float*)d_in[5];
    const float* fc1_b  = (const float*)d_in[6];
    const float* out_w  = (const float*)d_in[7];
    const float* out_b  = (const float*)d_in[8];
    unsigned int* ws = (unsigned int*)d_ws;

    prep<<<141, 256, 0, stream>>>(conv_w, char_e, fc1_w, out_w, ws);
    pos_fused<<<B_TOT / NI, 256, 0, stream>>>(input, emb, conv_b, fc1_b, out_b,
                                              ws, (float*)d_out);
}